// Round 2
// baseline (184.125 us; speedup 1.0000x reference)
//
#include <hip/hip_runtime.h>

// Problem constants
#define NTOK   2048
#define DIM    64
#define NCODES 50000
#define THRESH 100.0f
#define BIG    3.0e38f
#define MARGIN 4.0f      // rigorous 2E bound ~2.5; safety margin absorbs c2 rounding delta
#define NBLK   391       // 128-code MFMA blocks
#define BM32   1564      // 32-code screening blocks (391*4)
#define NCG    64        // code groups: first 7 have 7 blocks, rest 6 (7*7+57*6=391)
#define TB     16        // tokens per finalize WG
#define NFWG   (NTOK/TB) // 128 finalize WGs
#define NB16   98        // ceil(BM32/16) b-chunks per finalize iteration space

typedef __attribute__((ext_vector_type(8)))  __bf16 bf16x8;
typedef __attribute__((ext_vector_type(16))) float  float16;

__device__ __forceinline__ unsigned short f2bf(float f) {
    union { float f; unsigned int u; } v; v.f = f;
    unsigned int r = v.u + 0x7FFF + ((v.u >> 16) & 1);
    return (unsigned short)(r >> 16);
}
__device__ __forceinline__ unsigned int pack2(float a, float b) {
    return (unsigned int)f2bf(a) | ((unsigned int)f2bf(b) << 16);
}
// log-depth max of 16 (pairwise tree; clang can fuse into v_max3 chains)
__device__ __forceinline__ float max16(const float16& v) {
    float a = fmaxf(v[0], v[1]),   b = fmaxf(v[2], v[3]);
    float c = fmaxf(v[4], v[5]),   d = fmaxf(v[6], v[7]);
    float e = fmaxf(v[8], v[9]),   f = fmaxf(v[10], v[11]);
    float g = fmaxf(v[12], v[13]), h = fmaxf(v[14], v[15]);
    a = fmaxf(a, b); c = fmaxf(c, d); e = fmaxf(e, f); g = fmaxf(g, h);
    return fmaxf(fmaxf(a, c), fmaxf(e, g));
}

// ---------------------------------------------------------------------------
// Kernel 1 (stage A): bf16 MFMA screening directly from fp32 inputs.
// Output layout is TRANSPOSED: bmT[b][token] (b = 32-code block, 0..1563).
// Epilogue stores 4 dwords/lane -> each store instr covers 64 consecutive
// tokens = 256 B contiguous. Write traffic = exactly 12.8 MB (round 1 showed
// 100 MB with token-major rows: 16 B/lane scatter -> ~8x line-granular
// amplification, kernel was write-drain-bound at 62 us).
// Grid: (64 code groups of 6-7 blocks) x (8 token supertiles of 256) = 512
// WGs = exactly 2/CU; gi mod 8 -> XCD: the 8 supertile copies of one code
// group share an XCD (fp32 codes L2-resident). Each WG's bmT dirty region is
// whole-line (256-token chunks are 1 KB line-aligned), no false sharing.
// ---------------------------------------------------------------------------
__global__ __launch_bounds__(256, 2)
void nn_stageA_kernel(const float* __restrict__ x,
                      const float* __restrict__ codes,
                      float* __restrict__ bmT) {
    __shared__ __bf16 cs[128 * 72];   // code tile, 144 B row stride
    __shared__ float  c2s[128];       // holds -c2/2 per tile row

    const int tid  = threadIdx.x;
    const int w    = tid >> 6;
    const int lane = tid & 63;
    const int l31  = lane & 31;
    const int h    = lane >> 5;
    const int gi   = blockIdx.x;
    const int g0   = 6 * gi + min(gi, 7);
    const int nb   = (gi < 7) ? 7 : 6;
    const int t0   = blockIdx.y * 256;
    const int row_ = tid >> 3;        // 0..31 within an 'it' stripe
    const int seg  = tid & 7;         // 8 lanes per 64-dim code row

    // B fragments (tokens w*64..w*64+63) from fp32 x, converted in-register.
    bf16x8 bfr[4][2];
#pragma unroll
    for (int s = 0; s < 4; ++s)
#pragma unroll
        for (int nj = 0; nj < 2; ++nj) {
            const float4* xp = (const float4*)(x +
                (size_t)(t0 + w * 64 + nj * 32 + l31) * DIM + s * 16 + h * 8);
            float4 a = xp[0], b = xp[1];
            uint4 u;
            u.x = pack2(a.x, a.y); u.y = pack2(a.z, a.w);
            u.z = pack2(b.x, b.y); u.w = pack2(b.z, b.w);
            bfr[s][nj] = *(bf16x8*)&u;
        }

    // code-tile register prefetch: 128 rows x 256 B fp32; 8 lanes/row, 32 B/lane
    float4 pra[4], prb[4];
    auto prefetch = [&](int blk) {
        int n0 = blk * 128;
#pragma unroll
        for (int it = 0; it < 4; ++it) {
            int n = n0 + it * 32 + row_;
            if (n < NCODES) {
                const float4* cp = (const float4*)(codes + (size_t)n * DIM + seg * 8);
                pra[it] = cp[0]; prb[it] = cp[1];
            } else {
                pra[it] = make_float4(0.f, 0.f, 0.f, 0.f);
                prb[it] = pra[it];
            }
        }
    };
    prefetch(g0);

    for (int t = 0; t < nb; ++t) {
        const int blk = g0 + t;
        __syncthreads();   // previous iter's readers done with cs/c2s

        // convert + store current tile (regs -> LDS, conflict-free writes);
        // c2s gets -c2/2 directly
#pragma unroll
        for (int it = 0; it < 4; ++it) {
            int row = it * 32 + row_;
            float4 a = pra[it], b = prb[it];
            float s = a.x * a.x;
            s = fmaf(a.y, a.y, s); s = fmaf(a.z, a.z, s); s = fmaf(a.w, a.w, s);
            s = fmaf(b.x, b.x, s); s = fmaf(b.y, b.y, s);
            s = fmaf(b.z, b.z, s); s = fmaf(b.w, b.w, s);
            s += __shfl_xor(s, 1);   // 8 seg-lanes hold one row: bits 0-2 of tid
            s += __shfl_xor(s, 2);
            s += __shfl_xor(s, 4);
            uint4 u;
            u.x = pack2(a.x, a.y); u.y = pack2(a.z, a.w);
            u.z = pack2(b.x, b.y); u.w = pack2(b.z, b.w);
            *(uint4*)&cs[row * 72 + seg * 8] = u;
            if (seg == 0)
                c2s[row] = (blk * 128 + row < NCODES) ? -0.5f * s : -0.5f * BIG;
        }
        if (t + 1 < nb) prefetch(blk + 1);   // latency hides under MFMA phase
        __syncthreads();

        // acc[mi][nj][r] = -c2[code_row]/2  (c2s reads are 2-addr broadcasts)
        // C/D: col = lane&31 (token), row = (r&3) + 8*(r>>2) + 4*h (code)
        float16 acc[4][2];
#pragma unroll
        for (int mi = 0; mi < 4; ++mi)
#pragma unroll
            for (int g2 = 0; g2 < 4; ++g2) {
                float4 c4 = *(float4*)&c2s[mi * 32 + g2 * 8 + 4 * h];
#pragma unroll
                for (int i = 0; i < 4; ++i) {
                    float iv = ((float*)&c4)[i];
                    acc[mi][0][g2 * 4 + i] = iv;
                    acc[mi][1][g2 * 4 + i] = iv;
                }
            }

        // K = 64 in 4 steps of 16; A from LDS, B from registers
#pragma unroll
        for (int s = 0; s < 4; ++s) {
            bf16x8 a[4];
#pragma unroll
            for (int mi = 0; mi < 4; ++mi)
                a[mi] = *(bf16x8*)&cs[(mi * 32 + l31) * 72 + s * 16 + h * 8];
#pragma unroll
            for (int mi = 0; mi < 4; ++mi)
#pragma unroll
                for (int nj = 0; nj < 2; ++nj)
                    acc[mi][nj] = __builtin_amdgcn_mfma_f32_32x32x16_bf16(
                        a[mi], bfr[s][nj], acc[mi][nj], 0, 0, 0);
        }

        // epilogue: per-token min-screen value per 32-code group mi.
        // lanes<32 carry tokens +0..31 (nj=0), lanes>=32 tokens +32..63 (nj=1).
        // TRANSPOSED store: 4 dword stores, each 256 B contiguous across wave.
        // (invalid rows carry ~-1.5e38 from -BIG/2 init -> never win the max;
        // an all-invalid group yields +3e38 -> never a candidate)
        float4 o[2];
#pragma unroll
        for (int nj = 0; nj < 2; ++nj)
#pragma unroll
            for (int mi = 0; mi < 4; ++mi) {
                float m = max16(acc[mi][nj]);
                m = fmaxf(m, __shfl_xor(m, 32));  // merge h halves (rows +4)
                ((float*)&o[nj])[mi] = -2.0f * m;
            }
        float4 ov = (lane < 32) ? o[0] : o[1];
        int token = t0 + w * 64 + lane;
#pragma unroll
        for (int mi = 0; mi < 4; ++mi)
            bmT[(size_t)(blk * 4 + mi) * NTOK + token] = ((float*)&ov)[mi];
    }
}

// ---------------------------------------------------------------------------
// Kernel 2 (finalize): 128 WGs x 16 tokens. Wave = 4 b-rows x 16 tokens, so
// bmT scans are coalesced (64 B contiguous per b-row). Pass 1: per-token min
// over all 1564 blocks (shfl_xor(16/32) + LDS reduce -> threshold). Pass 2:
// rescan (L2-resident) + inline ballot-driven exact-fp32 rescore of candidate
// blocks (whole wave per candidate, 2 lanes/code) -> per-wave per-token best
// in LDS, final (v,id) merge. No queue, no capacity bound, no global atomics.
// Rescore math identical to the round-1 passing kernel (fmaf order, pair
// shfl merge, on-the-fly c2/x2).
// ---------------------------------------------------------------------------
__global__ __launch_bounds__(256)
void nn_finalize_kernel(const float* __restrict__ x,
                        const float* __restrict__ codes,
                        const float* __restrict__ bmT,
                        int* __restrict__ out) {
    __shared__ float xs[TB * DIM];   // 4 KB staged x rows
    __shared__ float x2s[TB];
    __shared__ float thS[TB];
    __shared__ float gW[4][TB];
    __shared__ float bvW[4][TB];
    __shared__ int   biW[4][TB];

    const int tid  = threadIdx.x;
    const int w    = tid >> 6;
    const int lane = tid & 63;
    const int t0   = blockIdx.x * TB;
    const int tloc = lane & 15;       // token slot within wave
    const int bslt = lane >> 4;       // b-row slot within wave (0..3)

    // stage x rows into LDS (coalesced float4 per thread)
    {
        int tok = tid >> 4, seg = tid & 15;
        *(float4*)&xs[tok * DIM + seg * 4] =
            *(const float4*)(x + (size_t)(t0 + tok) * DIM + seg * 4);
    }
    // x2 per token — same 2-lane association as the rescore path
    if (tid < 2 * TB) {
        int tok = tid >> 1, hf = tid & 1;
        const float4* xp = (const float4*)(x + (size_t)(t0 + tok) * DIM + hf * 32);
        float s = 0.f;
#pragma unroll
        for (int q = 0; q < 8; ++q) {
            float4 a = xp[q];
            s = fmaf(a.x, a.x, s); s = fmaf(a.y, a.y, s);
            s = fmaf(a.z, a.z, s); s = fmaf(a.w, a.w, s);
        }
        s += __shfl_xor(s, 1);
        if (hf == 0) x2s[tok] = s;
    }
    if (tid < 64) { bvW[tid >> 4][tid & 15] = BIG; biW[tid >> 4][tid & 15] = 0x7fffffff; }

    // pass 1: per-token min over all screening blocks (coalesced scan)
    const float* bp = bmT + t0 + tloc;
    float g = BIG;
#pragma unroll 7
    for (int it = 0; it < NB16; ++it) {
        int b = it * 16 + (w << 2) + bslt;
        float v = (b < BM32) ? bp[(size_t)b * NTOK] : BIG;
        g = fminf(g, v);
    }
    g = fminf(g, __shfl_xor(g, 16));   // fold b-slot bit 4
    g = fminf(g, __shfl_xor(g, 32));   // fold b-slot bit 5
    if (lane < 16) gW[w][tloc] = g;
    __syncthreads();
    if (tid < TB)
        thS[tid] = fminf(fminf(gW[0][tid], gW[1][tid]),
                         fminf(gW[2][tid], gW[3][tid])) + MARGIN;
    __syncthreads();

    // pass 2: rescan (L2-hit) + inline rescore of candidates
    const int half = lane & 1;
    for (int it = 0; it < NB16; ++it) {
        int b = it * 16 + (w << 2) + bslt;
        float v = (b < BM32) ? bp[(size_t)b * NTOK] : BIG;
        unsigned long long mask = __ballot(v <= thS[tloc]);
        while (mask) {
            int l = __ffsll(mask) - 1;
            mask &= mask - 1;
            int bc = __shfl(b, l);         // candidate block (wave-uniform)
            int tc = l & 15;               // candidate token slot
            int n  = bc * 32 + (lane >> 1);
            bool valid = (n < NCODES);
            float d = 0.f, cq = 0.f;
            if (valid) {
                const float4* cp = (const float4*)(codes + (size_t)n * DIM + half * 32);
                const float4* xp = (const float4*)&xs[tc * DIM + half * 32];
#pragma unroll
                for (int q = 0; q < 8; ++q) {
                    float4 c4 = cp[q];
                    float4 a  = xp[q];
                    d  = fmaf(a.x, c4.x, d);
                    d  = fmaf(a.y, c4.y, d);
                    d  = fmaf(a.z, c4.z, d);
                    d  = fmaf(a.w, c4.w, d);
                    cq = fmaf(c4.x, c4.x, cq);
                    cq = fmaf(c4.y, c4.y, cq);
                    cq = fmaf(c4.z, c4.z, cq);
                    cq = fmaf(c4.w, c4.w, cq);
                }
            }
            d  += __shfl_xor(d, 1);    // full 64-dim dot in both pair lanes
            cq += __shfl_xor(cq, 1);   // full ||c||^2 in both pair lanes
            float d2 = valid ? fmaxf(fmaf(-2.f, d, x2s[tc] + cq), 0.f) : BIG;
            int   ni = valid ? n : 0x7fffffff;
#pragma unroll
            for (int m = 1; m < 64; m <<= 1) {
                float vv = __shfl_xor(d2, m);
                int   ii = __shfl_xor(ni, m);
                if (vv < d2 || (vv == d2 && ii < ni)) { d2 = vv; ni = ii; }
            }
            if (lane == 0) {
                if (d2 < bvW[w][tc] || (d2 == bvW[w][tc] && ni < biW[w][tc])) {
                    bvW[w][tc] = d2; biW[w][tc] = ni;
                }
            }
        }
    }
    __syncthreads();
    if (tid < TB) {
        float fb = BIG;
        int   fi = 0x7fffffff;
#pragma unroll
        for (int i = 0; i < 4; ++i) {
            float vv = bvW[i][tid];
            int   ii = biW[i][tid];
            if (vv < fb || (vv == fb && ii < fi)) { fb = vv; fi = ii; }
        }
        out[t0 + tid] = (fb <= THRESH) ? fi : -1;
    }
}

// ---------------------------------------------------------------------------
// Workspace: bmT[1564][2048]f only (~12.8 MB), block-major.
// ---------------------------------------------------------------------------
extern "C" void kernel_launch(void* const* d_in, const int* in_sizes, int n_in,
                              void* d_out, int out_size, void* d_ws, size_t ws_size,
                              hipStream_t stream) {
    const float* x     = (const float*)d_in[0];  // [2,1024,64]
    const float* codes = (const float*)d_in[1];  // [50000,64]
    float* bmT = (float*)d_ws;
    int* out = (int*)d_out;

    nn_stageA_kernel<<<dim3(NCG, 8), 256, 0, stream>>>(x, codes, bmT);
    nn_finalize_kernel<<<NFWG, 256, 0, stream>>>(x, codes, bmT, out);
}